// Round 6
// baseline (246.493 us; speedup 1.0000x reference)
//
#include <hip/hip_runtime.h>

// GraphConv: out = relu( D * A_hat * D * x * W ),  B=8, N=2048, F=O=128, fp32.
// R11: R5 base; ONE change: yt stored TILED as yt_t[b][kt][o][32] (8 KB
//   contiguous per K-tile = exact LDS image), so K3's B-staging glds ops are
//   FULLY contiguous 1-KB bursts instead of 16 scattered 64-B segments.
// Theory: R9/R10 proved K3 is not vmcnt-latency-bound (two pipeline depths
//   both neutral). Per-CU accounting (~937 cyc/iter vs ~150 cyc work) points
//   at VMEM transaction service rate: every K3 load shatters into 16
//   segments (rows 4-8 KB apart). d_kernel streams the same adj at 4.8 TB/s
//   with contiguous ops — coalescing is the lever, not pipelining.
// K1 unchanged. K2 writes tiled layout. K3 = R5 structure + tiled B reads.

typedef __bf16 bf16x8 __attribute__((ext_vector_type(8)));
typedef float  f32x4  __attribute__((ext_vector_type(4)));

#define NN 2048
#define NB 8

__device__ __forceinline__ void load_lds16(__bf16* lds, const __bf16* g) {
    // per-lane global src; LDS dest = wave-uniform base + lane*16
    __builtin_amdgcn_global_load_lds(
        (const __attribute__((address_space(1))) void*)g,
        (__attribute__((address_space(3))) void*)lds, 16, 0, 0);
}

// ---------------- K1: degree vector + Wt convert in tail blocks ----------
__global__ __launch_bounds__(256) void d_kernel(const float* __restrict__ adj,
                                                float* __restrict__ dvec,
                                                const float* __restrict__ W,
                                                __bf16* __restrict__ Wt) {
    if (blockIdx.x >= NB * NN / 4) {
        int idx = (blockIdx.x - NB * NN / 4) * 256 + threadIdx.x;
        int f = idx >> 7, o = idx & 127;
        Wt[o * 128 + f] = (__bf16)W[idx];
        return;
    }
    const int lane = threadIdx.x & 63;
    const int row  = blockIdx.x * 4 + (threadIdx.x >> 6);   // one wave per row
    const float* rp = adj + (size_t)row * NN;
    float4 s4 = {0.f, 0.f, 0.f, 0.f};
#pragma unroll
    for (int it = 0; it < 8; ++it) {
        float4 v = *(const float4*)(rp + it * 256 + lane * 4);
        s4.x += v.x; s4.y += v.y; s4.z += v.z; s4.w += v.w;
    }
    float s = (s4.x + s4.y) + (s4.z + s4.w);
#pragma unroll
    for (int off = 32; off; off >>= 1) s += __shfl_down(s, off);
    if (lane == 0) {
        int n = row & (NN - 1);
        float sh = s - rp[n] + 1.0f;            // zero diag, add self-loop
        dvec[row] = 1.0f / (1e-6f + sqrtf(sh));
    }
}

// ------- K2: yt_t[b][m>>5][o][m&31] = bf16(d[m] * (x@W)[m,o]), LDS-free --
__global__ __launch_bounds__(256) void xw_kernel(const float* __restrict__ x,
                                                 const __bf16* __restrict__ Wt,
                                                 const float* __restrict__ dvec,
                                                 __bf16* __restrict__ yt) {
    const int lane = threadIdx.x & 63;
    const int wave = threadIdx.x >> 6;
    const int b    = blockIdx.x & 7;
    const int mt   = (blockIdx.x >> 3) * 4 + wave;   // 0..127
    const int m0   = mt * 16;
    const int kgrp = (lane >> 4) * 8;
    const float* xp = x + ((size_t)b * NN + m0 + (lane & 15)) * 128 + kgrp;

    f32x4 acc[8];
#pragma unroll
    for (int i = 0; i < 8; ++i) acc[i] = (f32x4){0.f, 0.f, 0.f, 0.f};

#pragma unroll
    for (int kt = 0; kt < 4; ++kt) {
        f32x4 a0 = *(const f32x4*)(xp + kt * 32);
        f32x4 a1 = *(const f32x4*)(xp + kt * 32 + 4);
        float av[8] = {a0.x, a0.y, a0.z, a0.w, a1.x, a1.y, a1.z, a1.w};
        bf16x8 af;
#pragma unroll
        for (int j = 0; j < 8; ++j) af[j] = (__bf16)av[j];
#pragma unroll
        for (int nb = 0; nb < 8; ++nb) {
            bf16x8 bfv = *(const bf16x8*)(Wt + (nb * 16 + (lane & 15)) * 128 +
                                          kt * 32 + kgrp);
            acc[nb] = __builtin_amdgcn_mfma_f32_16x16x32_bf16(af, bfv, acc[nb], 0, 0, 0);
        }
    }
    const int col0 = lane & 15;
    const int rq   = (lane >> 4) * 4;
#pragma unroll
    for (int r = 0; r < 4; ++r) {
        int m = m0 + rq + r;
        float dm = dvec[b * NN + m];
        // tiled: yt_t[b][m>>5][o][m&31]
        __bf16* yrow = yt + (((size_t)b * 64 + (m >> 5)) * 128) * 32 + (m & 31);
#pragma unroll
        for (int nb = 0; nb < 8; ++nb) {
            int o = nb * 16 + col0;
            yrow[(size_t)o * 32] = (__bf16)(acc[nb][r] * dm);
        }
    }
}

// ---------------- K3: staged GEMM, contiguous-tile B staging -------------
// Block 256 thr: 32 rows x 128 cols; wave w: rows (w&1)*16, cols (w>>1)*64.
// grid 512 (2 blocks/CU), b = blockIdx.x & 7.
__global__ __launch_bounds__(256) void gemm_kernel(const float* __restrict__ adj,
                                                   const __bf16* __restrict__ yt,
                                                   const float* __restrict__ dvec,
                                                   float* __restrict__ out) {
    __shared__ alignas(16) __bf16 sB[2][128][32];   // [o][k] image of one tile

    const int tid  = threadIdx.x;
    const int wave = tid >> 6;
    const int lane = tid & 63;
    const int b    = blockIdx.x & 7;
    const int tile = blockIdx.x >> 3;            // 0..63
    const int rsel = (wave & 1) * 16;
    const int csel = (wave >> 1) * 64;
    const int kgrp = (lane >> 4) * 8;
    const int l15  = lane & 15;

    // A: direct from global fp32, k-contiguous fragment
    const int arow_loc = tile * 32 + rsel + l15;
    const float* ap = adj + ((size_t)b * NN + arow_loc) * NN + kgrp;

    // B: tiled yt_t[b][kt][o][32]; wave w copies elements [w*1024, w*1024+1024)
    // of each 4096-element tile as two 1-KB CONTIGUOUS glds bursts.
    const __bf16* ytb   = yt + (size_t)b * 64 * 128 * 32;   // batch base
    const __bf16* b_src = ytb + wave * 1024 + lane * 8;     // + kt*4096 (+512)

    f32x4 acc[4];
#pragma unroll
    for (int i = 0; i < 4; ++i) acc[i] = (f32x4){0.f, 0.f, 0.f, 0.f};

    // preload iter 0
    load_lds16(&sB[0][wave * 32][0], b_src);
    load_lds16(&sB[0][wave * 32 + 16][0], b_src + 512);
    f32x4 ca0 = *(const f32x4*)(ap);
    f32x4 ca1 = *(const f32x4*)(ap + 4);

    for (int kt = 0; kt < 64; ++kt) {
        const int cur = kt & 1;
        __syncthreads();   // drains loads issued last iter (glds + A regs)

        // issue NEXT iter's loads first: in flight through the MFMA phase
        f32x4 na0, na1;
        if (kt + 1 < 64) {
            const __bf16* bs = b_src + (size_t)(kt + 1) * 4096;
            load_lds16(&sB[cur ^ 1][wave * 32][0], bs);
            load_lds16(&sB[cur ^ 1][wave * 32 + 16][0], bs + 512);
            na0 = *(const f32x4*)(ap + (kt + 1) * 32);
            na1 = *(const f32x4*)(ap + (kt + 1) * 32 + 4);
        }

        // convert current A regs (loaded last iter, drained by the barrier)
        bf16x8 af;
        af[0] = (__bf16)ca0.x; af[1] = (__bf16)ca0.y;
        af[2] = (__bf16)ca0.z; af[3] = (__bf16)ca0.w;
        af[4] = (__bf16)ca1.x; af[5] = (__bf16)ca1.y;
        af[6] = (__bf16)ca1.z; af[7] = (__bf16)ca1.w;

#pragma unroll
        for (int nb = 0; nb < 4; ++nb) {
            bf16x8 bfv = *(const bf16x8*)(&sB[cur][csel + nb * 16 + l15][kgrp]);
            acc[nb] = __builtin_amdgcn_mfma_f32_16x16x32_bf16(af, bfv, acc[nb], 0, 0, 0);
        }
        ca0 = na0; ca1 = na1;
    }

    // epilogue: diag correction + row scale + relu
    //   out = d[n] * (acc + (1 - adj[n,n]) * yt[o][n])
    const int rq = (lane >> 4) * 4;
#pragma unroll
    for (int r = 0; r < 4; ++r) {
        int n_loc = tile * 32 + rsel + rq + r;
        size_t grow = (size_t)b * NN + n_loc;
        float dn   = dvec[grow];
        float cfac = 1.0f - adj[grow * NN + n_loc];
        const __bf16* ycol = ytb + ((size_t)(n_loc >> 5) * 128) * 32 + (n_loc & 31);
#pragma unroll
        for (int nb = 0; nb < 4; ++nb) {
            int o = csel + nb * 16 + l15;
            float yp = (float)ycol[(size_t)o * 32];
            float v = (acc[nb][r] + cfac * yp) * dn;
            out[grow * 128 + o] = v > 0.f ? v : 0.f;
        }
    }
}

extern "C" void kernel_launch(void* const* d_in, const int* in_sizes, int n_in,
                              void* d_out, int out_size, void* d_ws, size_t ws_size,
                              hipStream_t stream) {
    const float* x   = (const float*)d_in[0];   // [8,2048,128]
    const float* adj = (const float*)d_in[1];   // [8,2048,2048]
    const float* W   = (const float*)d_in[2];   // [128,128]
    float* out = (float*)d_out;

    char* ws = (char*)d_ws;
    float*  dvec = (float*)ws;                          // 64 KB
    __bf16* Wt   = (__bf16*)(ws + (64 << 10));          // 32 KB
    __bf16* yt   = (__bf16*)(ws + (128 << 10));         // 4 MB  [B][64][128][32]

    hipLaunchKernelGGL(d_kernel, dim3(NB * NN / 4 + 64), dim3(256), 0, stream,
                       adj, dvec, W, Wt);
    hipLaunchKernelGGL(xw_kernel, dim3(256), dim3(256), 0, stream, x, Wt, dvec, yt);
    hipLaunchKernelGGL(gemm_kernel, dim3(512), dim3(256), 0, stream,
                       adj, yt, dvec, out);
}